// Round 10
// baseline (4385.217 us; speedup 1.0000x reference)
//
#include <hip/hip_runtime.h>

#define SS 2048
#define HH 64

typedef _Float16 h2v __attribute__((ext_vector_type(2)));
typedef unsigned int uint;

__device__ __forceinline__ float fdot2f(uint w, uint x, float c) {
#if __has_builtin(__builtin_amdgcn_fdot2)
    return __builtin_amdgcn_fdot2(__builtin_bit_cast(h2v, w),
                                  __builtin_bit_cast(h2v, x), c, false);
#else
    h2v a = __builtin_bit_cast(h2v, w), bb = __builtin_bit_cast(h2v, x);
    return fmaf((float)a[0], (float)bb[0], fmaf((float)a[1], (float)bb[1], c));
#endif
}
__device__ __forceinline__ uint pack2(float a, float b) {
    h2v v = {(_Float16)a, (_Float16)b};
    return __builtin_bit_cast(uint, v);
}
__device__ __forceinline__ unsigned short f16bits(float a) {
    return __builtin_bit_cast(unsigned short, (_Float16)a);
}
__device__ __forceinline__ float fast_tanh(float x) {
    float ax = fabsf(x);
    float e = __expf(-2.0f * ax);
    float r = (1.0f - e) * __builtin_amdgcn_rcpf(1.0f + e);
    return copysignf(r, x);
}
__device__ __forceinline__ float fast_sigmoid(float x) {
    return __builtin_amdgcn_rcpf(1.0f + __expf(-x));
}

__global__ __launch_bounds__(256)
__attribute__((amdgpu_waves_per_eu(1, 1)))
void pgjanet_kernel(
    const float* __restrict__ x,     // [B,S,2]
    const float* __restrict__ h0,    // [1,B,H]
    const float* __restrict__ Wa,    // [65,64]
    const float* __restrict__ ba,
    const float* __restrict__ Wp1,
    const float* __restrict__ bp1,
    const float* __restrict__ Wp2,
    const float* __restrict__ bp2,
    const float* __restrict__ Wz,    // [128,64]
    const float* __restrict__ bz,
    const float* __restrict__ Wh,    // [128,64]
    const float* __restrict__ bh,
    const float* __restrict__ Wout,  // [64,2]
    const float* __restrict__ bout,
    float* __restrict__ out)         // [B,S,2]
{
    const int b   = blockIdx.x;
    const int tid = threadIdx.x;     // 0..255
    const int j   = tid & 63;
    const int wid = tid >> 6;        // 0..3
    const int zoff = wid * 8;        // zh pair-slice base

    __shared__ float2 xs2[SS];                            // 16 KB
    __shared__ __align__(16) unsigned short hpk[4][64];   // per-wave h (f16)
    __shared__ __align__(16) unsigned short upk[4][64];   // per-wave u (f16)
    __shared__ float aLm[64], p1Lm[64], p2Lm[64];
    __shared__ float zhp[4][64];
    __shared__ float hhLm[64];
    __shared__ float pBm[4][64];
    __shared__ __align__(16) float hbufL[32 * 68];        // padded stash
    __shared__ __align__(16) float WoutT[2 * 68];
    __shared__ float boutS[2];

    // ---- stage x[b] (coalesced) + Wout^T ----
    {
        const float2* xb = (const float2*)(x + (size_t)b * SS * 2);
        #pragma unroll
        for (int it = 0; it < SS / 256; ++it)
            xs2[tid + it * 256] = xb[tid + it * 256];
    }
    if (tid < 64) {
        WoutT[0 * 68 + tid] = Wout[tid * 2 + 0];
        WoutT[1 * 68 + tid] = Wout[tid * 2 + 1];
    }
    if (tid < 2) boutS[tid] = bout[tid];

    // ---- per-wave weight slices (56 packed f16 pairs per lane) ----
    const float* mainW;
    float w0r = 0.f, bAr = 0.f;
    if (wid == 0)      { mainW = Wa  + HH; w0r = Wa[j];  bAr = ba[j];  }
    else if (wid == 1) { mainW = Wp1 + HH; w0r = Wp1[j]; bAr = bp1[j]; }
    else if (wid == 2) { mainW = Wp2 + HH; w0r = Wp2[j]; bAr = bp2[j]; }
    else               { mainW = Wh + 64 * HH; }          // hh (linear)

    uint wM[32], wZ8[8], wB[16];
    #pragma unroll
    for (int p = 0; p < 32; ++p)
        wM[p] = pack2(mainW[(2 * p) * HH + j], mainW[(2 * p + 1) * HH + j]);
    #pragma unroll
    for (int q = 0; q < 8; ++q) {
        const int p = zoff + q;
        wZ8[q] = pack2(Wz[(64 + 2 * p) * HH + j], Wz[(65 + 2 * p) * HH + j]);
    }
    const float* uW = (wid < 2 ? Wz : Wh) + ((wid & 1) * 32) * HH;
    #pragma unroll
    for (int p = 0; p < 16; ++p)
        wB[p] = pack2(uW[(2 * p) * HH + j], uW[(2 * p + 1) * HH + j]);

    // pin: opaque values can't be rematerialized/sunk into the loop
    #pragma unroll
    for (int k = 0; k < 32; ++k) asm volatile("" : "+v"(wM[k]));
    #pragma unroll
    for (int k = 0; k < 8; ++k)  asm volatile("" : "+v"(wZ8[k]));
    #pragma unroll
    for (int k = 0; k < 16; ++k) asm volatile("" : "+v"(wB[k]));

    const float bzR = bz[j];
    const float bhR = bh[j];

    // h carried in f32 registers (redundant in every wave); f16 copy per wave
    float hreg = h0[b * HH + j];
    hpk[wid][j] = f16bits(hreg);

    __syncthreads();

    for (int t = 0; t < SS; ++t) {
        // ---- h broadcast from OWN wave copy (same-wave DS ordering) ----
        const uint4* hp4 = (const uint4*)hpk[wid];
        uint4 hq[8];
        #pragma unroll
        for (int g = 0; g < 8; ++g) hq[g] = hp4[g];
        const uint* hu = (const uint*)hq;

        // ---- per-step scalar input ----
        const float2 xt = xs2[t];
        const float d = xt.x * xt.x + xt.y * xt.y;
        const float inv = (d > 0.f) ? __builtin_amdgcn_rsqf(d) : 0.f;
        float scal;
        if (wid == 0)      scal = d * inv;                        // amp
        else if (wid == 1) scal = (d > 0.f) ? xt.x * inv : 1.0f;  // cos
        else if (wid == 2) scal = xt.y * inv;                     // sin
        else               scal = 0.f;

        // ---- PHASE A: main matvec (32 pairs) + zh slice (8 pairs) ----
        float c0 = 0.f, c1 = 0.f, c2 = 0.f, c3 = 0.f;
        #pragma unroll
        for (int p = 0; p < 32; p += 4) {
            c0 = fdot2f(wM[p + 0], hu[p + 0], c0);
            c1 = fdot2f(wM[p + 1], hu[p + 1], c1);
            c2 = fdot2f(wM[p + 2], hu[p + 2], c2);
            c3 = fdot2f(wM[p + 3], hu[p + 3], c3);
        }
        const float pre = (c0 + c1) + (c2 + c3) + fmaf(scal, w0r, bAr);

        float z0 = 0.f, z1 = 0.f;
        #pragma unroll
        for (int q = 0; q < 8; q += 2) {
            z0 = fdot2f(wZ8[q + 0], hu[zoff + q + 0], z0);
            z1 = fdot2f(wZ8[q + 1], hu[zoff + q + 1], z1);
        }
        zhp[wid][j] = z0 + z1;

        if (wid == 0)      aLm[j]  = fast_tanh(pre);
        else if (wid == 1) p1Lm[j] = fast_tanh(pre);
        else if (wid == 2) p2Lm[j] = fast_tanh(pre);
        else               hhLm[j] = pre;
        __syncthreads();  // bar1: gates + zhp + hh visible

        // ---- u (per-lane) + own-copy broadcast + PHASE B ----
        {
            const float av  = aLm[j];
            const float p1v = p1Lm[j];
            const float p2v = p2Lm[j];
            const float uu = av * p1v * p2v * (1.f - av) * (1.f - p1v) * (1.f - p2v);
            upk[wid][j] = f16bits(uu);

            // own-wave broadcast reads of the 16-pair slice (4 x b128)
            const uint4* up4 = (const uint4*)(&upk[wid][0] + (wid & 1) * 32);
            uint4 uq[4];
            #pragma unroll
            for (int g = 0; g < 4; ++g) uq[g] = up4[g];
            const uint* uu32 = (const uint*)uq;

            // fold partials while u-reads are in flight
            float fold;
            if (wid == 0)      fold = zhp[0][j] + zhp[1][j];
            else if (wid == 1) fold = zhp[2][j] + zhp[3][j];
            else if (wid == 2) fold = hhLm[j];
            else               fold = 0.f;

            float b0 = 0.f, b1 = 0.f, b2 = 0.f, b3 = 0.f;
            #pragma unroll
            for (int p = 0; p < 16; p += 4) {
                b0 = fdot2f(wB[p + 0], uu32[p + 0], b0);
                b1 = fdot2f(wB[p + 1], uu32[p + 1], b1);
                b2 = fdot2f(wB[p + 2], uu32[p + 2], b2);
                b3 = fdot2f(wB[p + 3], uu32[p + 3], b3);
            }
            pBm[wid][j] = (b0 + b1) + (b2 + b3) + fold;
        }
        __syncthreads();  // bar2: pB visible

        // ---- COMBINE (all waves redundantly; h stays f32 in registers) ----
        {
            const float zpre = pBm[0][j] + pBm[1][j] + bzR;
            const float hpre = pBm[2][j] + pBm[3][j] + bhR;
            const float zz = fast_sigmoid(zpre);
            const float hc = fast_tanh(hpre);
            hreg = fmaf(zz, hreg - hc, hc);
            hpk[wid][j] = f16bits(hreg);          // own copy for next step
            if (wid == 3) hbufL[(t & 31) * 68 + j] = hreg;
        }
        // no bar3: hpk/upk are own-wave; aLm/zhp/hhLm rewritten only after
        // bar2(t); pBm rewritten only after bar1(t+1) — all hazards covered.

        // ---- output flush every 32 steps (wave 3, within-wave in-order) ----
        if ((t & 31) == 31 && wid == 3) {
            const int r = j >> 1, o = j & 1;
            const float4* hrow = (const float4*)(hbufL + r * 68);
            const float4* wrow = (const float4*)(WoutT + o * 68);
            float acc = 0.f;
            #pragma unroll
            for (int k = 0; k < 16; ++k) {
                float4 hv = hrow[k], wv = wrow[k];
                acc += hv.x * wv.x + hv.y * wv.y + hv.z * wv.z + hv.w * wv.w;
            }
            out[((size_t)b * SS + (t - 31 + r)) * 2 + o] = acc + boutS[o];
        }
    }
}

extern "C" void kernel_launch(void* const* d_in, const int* in_sizes, int n_in,
                              void* d_out, int out_size, void* d_ws, size_t ws_size,
                              hipStream_t stream) {
    const float* x    = (const float*)d_in[0];
    const float* h0   = (const float*)d_in[1];
    const float* Wa   = (const float*)d_in[2];
    const float* ba   = (const float*)d_in[3];
    const float* Wp1  = (const float*)d_in[4];
    const float* bp1  = (const float*)d_in[5];
    const float* Wp2  = (const float*)d_in[6];
    const float* bp2  = (const float*)d_in[7];
    const float* Wz   = (const float*)d_in[8];
    const float* bz   = (const float*)d_in[9];
    const float* Wh   = (const float*)d_in[10];
    const float* bh   = (const float*)d_in[11];
    const float* Wout = (const float*)d_in[12];
    const float* bout = (const float*)d_in[13];
    float* out = (float*)d_out;

    pgjanet_kernel<<<256, 256, 0, stream>>>(x, h0, Wa, ba, Wp1, bp1, Wp2, bp2,
                                            Wz, bz, Wh, bh, Wout, bout, out);
}